// Round 8
// baseline (240.584 us; speedup 1.0000x reference)
//
#include <hip/hip_runtime.h>
#include <hip/hip_bf16.h>

// HorizonTemporalSelfAttention: multi-scale deformable attention
// bs=2, nq=16384, E=256, NH=8, NL=4, NP=4, d=32, total tokens=21760
//
// R7:  logits stored as per-(b,h,q) 48-half records [32 off | 16 attn].
// R8:  XCD-aware sampler swizzle (FETCH 126->43 MB; taps L2-resident).
// R9 (REVERTED): 1-thread-per-query broke intra-line coalescing. Lesson:
//      keep 4 lanes x 16B = one 64B segment per tap in ONE instruction.
// R12/R13: reg-pipeline attempts: allocator sank the loads (VGPR stuck 52).
// R14: level-split (thread = q,l,c4). Occupancy 38->64, VALU 48->67 --
//      latency now hidden, but 16x-duplicated softmax ate the win (81 us).
// R15: softmax moved into the GEMM epilogue. In the n0=256 tile the 16
//      attn logits of one (h,q) sit in 16 adjacent lanes of one register
//      -> shfl_xor(1,2,4,8) softmax, slots 32..47 now hold NORMALIZED f16
//      weights. Sampler softmax deleted entirely (reads half4 of weights).

typedef __attribute__((ext_vector_type(4))) float    float4v;
typedef __attribute__((ext_vector_type(8))) _Float16 half8;
typedef __attribute__((ext_vector_type(4))) _Float16 half4;
typedef __attribute__((ext_vector_type(2))) _Float16 half2v;

#define NQ    16384
#define NTOK  21760
#define LREC  48          // halves per (b,h,q) record: 32 off | 16 weights

#define GEMM_BLOCKS 768   // 256 M-tiles x 3 N-tiles
#define CONV_BLOCKS 10880 // 2785280 float4 / 256

union H8 { half8 v; half2v p[4]; };

// ---------------- K-F: fused GEMM + value convert ----------------
#define LDSTR 88
__global__ __launch_bounds__(256) void fused_kernel(
    const float* __restrict__ qf,
    const float* __restrict__ Woff, const float* __restrict__ Wattn,
    const float* __restrict__ boff, const float* __restrict__ battn,
    const float* __restrict__ val,
    _Float16* __restrict__ lh, _Float16* __restrict__ vh) {
  const int tid = threadIdx.x;

  if (blockIdx.x >= GEMM_BLOCKS) {
    // ---- value convert: f32 -> f16, one float4 per thread ----
    int i = (blockIdx.x - GEMM_BLOCKS) * 256 + tid;
    float4v v = ((const float4v*)val)[i];
    half4 o;
    o[0] = (_Float16)v[0]; o[1] = (_Float16)v[1];
    o[2] = (_Float16)v[2]; o[3] = (_Float16)v[3];
    ((half4*)vh)[i] = o;
    return;
  }

  // ---- GEMM: logits = q @ Wcat^T + bias -> per-(b,h,q) records ----
  __shared__ _Float16 As[128 * LDSTR];
  __shared__ _Float16 Bs[128 * LDSTR];

  const int lane = tid & 63;
  const int wv   = tid >> 6;
  const int wm   = wv >> 1, wn = wv & 1;
  const int quad = lane >> 4;
  const int r    = lane & 15;
  const int blockM = (blockIdx.x & 255) * 128;
  const int n0     = (blockIdx.x >> 8) * 128;

  float4v acc[4][4];
#pragma unroll
  for (int i = 0; i < 4; ++i)
#pragma unroll
    for (int j = 0; j < 4; ++j) acc[i][j] = (float4v){0.f, 0.f, 0.f, 0.f};

  for (int kc = 0; kc < 4; ++kc) {
    const int k0 = kc * 64;
    if (kc) __syncthreads();
    // A: 128 rows x 16 float4 k-cols, f32 -> f16
#pragma unroll
    for (int it = 0; it < 8; ++it) {
      int idx = it * 256 + tid;
      int row = idx >> 4, k4 = idx & 15;
      float4v v = *(const float4v*)(qf + (size_t)(blockM + row) * 256 + k0 + k4 * 4);
      half4 o;
      o[0] = (_Float16)v[0]; o[1] = (_Float16)v[1];
      o[2] = (_Float16)v[2]; o[3] = (_Float16)v[3];
      *(half4*)&As[row * LDSTR + k4 * 4] = o;
    }
    // B: 128 rows x 16 float4 k-cols from Wcat f32 (L2-resident, 394 KB)
#pragma unroll
    for (int it = 0; it < 8; ++it) {
      int idx = it * 256 + tid;
      int row = idx >> 4, k4 = idx & 15;
      int n = n0 + row;
      const float* src = (n < 256) ? (Woff + (size_t)n * 256)
                                   : (Wattn + (size_t)(n - 256) * 256);
      float4v v = *(const float4v*)(src + k0 + k4 * 4);
      half4 o;
      o[0] = (_Float16)v[0]; o[1] = (_Float16)v[1];
      o[2] = (_Float16)v[2]; o[3] = (_Float16)v[3];
      *(half4*)&Bs[row * LDSTR + k4 * 4] = o;
    }
    __syncthreads();

#pragma unroll
    for (int kf = 0; kf < 2; ++kf) {
      const int ko = kf * 32 + quad * 8;
      half8 af[4], bf[4];
#pragma unroll
      for (int mi = 0; mi < 4; ++mi)
        af[mi] = *(const half8*)&As[(wm * 64 + mi * 16 + r) * LDSTR + ko];
#pragma unroll
      for (int ni = 0; ni < 4; ++ni)
        bf[ni] = *(const half8*)&Bs[(wn * 64 + ni * 16 + r) * LDSTR + ko];
#pragma unroll
      for (int mi = 0; mi < 4; ++mi)
#pragma unroll
        for (int ni = 0; ni < 4; ++ni)
          acc[mi][ni] = __builtin_amdgcn_mfma_f32_16x16x32_f16(af[mi], bf[ni], acc[mi][ni], 0, 0, 0);
    }
  }

  // epilogue. n0 is block-uniform: {0,128} = offset logits, {256} = attn.
  if (n0 == 256) {
    // attn tile: the 16 logits of one (h,q) record live in lanes r=0..15 of
    // the same quad group (slot = r, h = wn*4+ni, q = mb+reg). Softmax via
    // shfl_xor(1,2,4,8) (stays inside the 16-lane group), store f16 weight.
#pragma unroll
    for (int mi = 0; mi < 4; ++mi) {
      const int mb = blockM + wm * 64 + mi * 16 + quad * 4;
#pragma unroll
      for (int ni = 0; ni < 4; ++ni) {
        const int n = n0 + wn * 64 + ni * 16 + r;
        const float bias = battn[n - 256];
        const int h    = (n - 256) >> 4;      // == wn*4 + ni
        const int slot = 32 + ((n - 256) & 15); // == 32 + r
#pragma unroll
        for (int reg = 0; reg < 4; ++reg) {
          const int bq = mb + reg;
          const int b = bq >> 14, q = bq & 16383;
          const float v = acc[mi][ni][reg] + bias;
          float m = v;
          m = fmaxf(m, __shfl_xor(m, 1));
          m = fmaxf(m, __shfl_xor(m, 2));
          m = fmaxf(m, __shfl_xor(m, 4));
          m = fmaxf(m, __shfl_xor(m, 8));
          const float e = __expf(v - m);
          float s = e;
          s += __shfl_xor(s, 1);
          s += __shfl_xor(s, 2);
          s += __shfl_xor(s, 4);
          s += __shfl_xor(s, 8);
          lh[((size_t)(b * 8 + h) * NQ + q) * LREC + slot] =
              (_Float16)(e * (1.0f / s));
        }
      }
    }
  } else {
    // offset tiles (n < 256): h = n>>5, slot = n&31, unchanged
#pragma unroll
    for (int mi = 0; mi < 4; ++mi) {
      const int mb = blockM + wm * 64 + mi * 16 + quad * 4;
#pragma unroll
      for (int ni = 0; ni < 4; ++ni) {
        const int n = n0 + wn * 64 + ni * 16 + r;
        const float bias = boff[n];
        const int h    = n >> 5;
        const int slot = n & 31;
#pragma unroll
        for (int reg = 0; reg < 4; ++reg) {
          const int bq = mb + reg;
          const int b = bq >> 14, q = bq & 16383;
          lh[((size_t)(b * 8 + h) * NQ + q) * LREC + slot] =
              (_Float16)(acc[mi][ni][reg] + bias);
        }
      }
    }
  }
}

// ---------------- K-S: sampling (level-split, weights precomputed) ----------------
// grid 16384 flat; xcd = bid&7, local = bid>>3 (0..2047),
// hb = xcd*2 + (local>>10), qt = local&1023 -> 16 queries per block.
// thread: c4 = tid&3 (channels c4*8..+7), l = (tid>>2)&3, qi = tid>>4.
// Quad of each (q,l) issues 4x16B adjacent per tap -> one 64B segment.
__global__ __launch_bounds__(256) void sample_kernel(
    const _Float16* __restrict__ vh, const float* __restrict__ refp,
    const _Float16* __restrict__ lh, float* __restrict__ out) {
  const int bid   = blockIdx.x;
  const int xcd   = bid & 7;
  const int local = bid >> 3;
  const int hb    = xcd * 2 + (local >> 10);  // 0..15, == b*8+h
  const int qt    = local & 1023;
  const int h     = hb & 7;
  const int b     = hb >> 3;
  const int tid = threadIdx.x;
  const int c4 = tid & 3;
  const int l  = (tid >> 2) & 3;
  const int qi = tid >> 4;                    // 0..15
  const int q  = qt * 16 + qi;
  const size_t bq = (size_t)b * NQ + q;
  const _Float16* rec = lh + ((size_t)hb * NQ + q) * LREC;

  // own level's 8 offsets (layout within record: l*8 + p*2 + xy)
  const half8 oh = *(const half8*)(rec + l * 8);
  // own level's 4 NORMALIZED softmax weights (slots 32 + l*4 + p)
  const half4 ownw = *(const half4*)(rec + 32 + l * 4);

  float4v rp0 = *(const float4v*)(refp + bq * 8);
  float4v rp1 = *(const float4v*)(refp + bq * 8 + 4);
  const float rpx[4] = {rp0[0], rp0[2], rp1[0], rp1[2]};
  const float rpy[4] = {rp0[1], rp0[3], rp1[1], rp1[3]};

  // level geometry (uniform per thread; scalar, no runtime-indexed arrays)
  const int   W    = 128 >> l;
  const float fW   = (float)W;
  const int   base = (l == 0) ? 0 : (l == 1) ? 16384 : (l == 2) ? 20480 : 21504;
  const _Float16* vlev = vh + (size_t)b * NTOK * 256 + h * 32 + c4 * 8
                            + (size_t)base * 256;

  half2v accl0 = (half2v){(_Float16)0, (_Float16)0};
  half2v accl1 = (half2v){(_Float16)0, (_Float16)0};
  half2v accl2 = (half2v){(_Float16)0, (_Float16)0};
  half2v accl3 = (half2v){(_Float16)0, (_Float16)0};

#pragma unroll
  for (int p = 0; p < 4; ++p) {
    const float a  = (float)ownw[p];          // precomputed softmax weight
    const float ox = (float)oh[p * 2];
    const float oy = (float)oh[p * 2 + 1];
    // (ref + off/shape)*2-1 through grid_sample == ref*W + off - 0.5
    const float x = rpx[p] * fW + ox - 0.5f;
    const float y = rpy[p] * fW + oy - 0.5f;
    const float xf = floorf(x), yf = floorf(y);
    const float fx = x - xf, fy = y - yf;
    const int ix = (int)xf, iy = (int)yf;
    const int ix0 = min(max(ix, 0), W - 1);
    const int ix1 = min(max(ix + 1, 0), W - 1);
    const int iy0 = min(max(iy, 0), W - 1);
    const int iy1 = min(max(iy + 1, 0), W - 1);
    const float wx0 = ((unsigned)ix       < (unsigned)W) ? 1.f - fx : 0.f;
    const float wx1 = ((unsigned)(ix + 1) < (unsigned)W) ? fx       : 0.f;
    const float wy0 = ((unsigned)iy       < (unsigned)W) ? 1.f - fy : 0.f;
    const float wy1 = ((unsigned)(iy + 1) < (unsigned)W) ? fy       : 0.f;
    const _Float16 w00 = (_Float16)(a * wx0 * wy0);
    const _Float16 w01 = (_Float16)(a * wx1 * wy0);
    const _Float16 w10 = (_Float16)(a * wx0 * wy1);
    const _Float16 w11 = (_Float16)(a * wx1 * wy1);
    const half2v h00 = (half2v){w00, w00};
    const half2v h01 = (half2v){w01, w01};
    const half2v h10 = (half2v){w10, w10};
    const half2v h11 = (half2v){w11, w11};
    const _Float16* r0 = vlev + (size_t)(iy0 * W) * 256;
    const _Float16* r1 = vlev + (size_t)(iy1 * W) * 256;
    H8 t00, t01, t10, t11;
    t00.v = *(const half8*)(r0 + ix0 * 256);
    t01.v = *(const half8*)(r0 + ix1 * 256);
    t10.v = *(const half8*)(r1 + ix0 * 256);
    t11.v = *(const half8*)(r1 + ix1 * 256);
    accl0 += h00 * t00.p[0] + h01 * t01.p[0] + h10 * t10.p[0] + h11 * t11.p[0];
    accl1 += h00 * t00.p[1] + h01 * t01.p[1] + h10 * t10.p[1] + h11 * t11.p[1];
    accl2 += h00 * t00.p[2] + h01 * t01.p[2] + h10 * t10.p[2] + h11 * t11.p[2];
    accl3 += h00 * t00.p[3] + h01 * t01.p[3] + h10 * t10.p[3] + h11 * t11.p[3];
  }

  // flush level accumulator to f32 (channels c4*8 .. c4*8+7)
  float acc0[4], acc1[4];
  acc0[0] = (float)accl0[0]; acc0[1] = (float)accl0[1];
  acc0[2] = (float)accl1[0]; acc0[3] = (float)accl1[1];
  acc1[0] = (float)accl2[0]; acc1[1] = (float)accl2[1];
  acc1[2] = (float)accl3[0]; acc1[3] = (float)accl3[1];

  // LDS cross-level reduce + transposed coalesced store.
  __shared__ float sm[4][16][33];
#pragma unroll
  for (int j = 0; j < 4; ++j) {
    sm[l][qi][c4 * 8 + j]     = acc0[j];
    sm[l][qi][c4 * 8 + 4 + j] = acc1[j];
  }
  __syncthreads();
  // 512 outputs (32c x 16q), 2 per thread; sum levels IN ORDER.
  const size_t obase = ((size_t)b * 256 + h * 32) * NQ + qt * 16;
#pragma unroll
  for (int i = 0; i < 2; ++i) {
    const int idx = i * 256 + tid;
    const int c  = idx >> 4;
    const int ql = idx & 15;
    const float v = ((sm[0][ql][c] + sm[1][ql][c]) + sm[2][ql][c]) + sm[3][ql][c];
    out[obase + (size_t)c * NQ + ql] = v;
  }
}

extern "C" void kernel_launch(void* const* d_in, const int* in_sizes, int n_in,
                              void* d_out, int out_size, void* d_ws, size_t ws_size,
                              hipStream_t stream) {
  const float* query = (const float*)d_in[0];
  const float* value = (const float*)d_in[1];
  const float* refp  = (const float*)d_in[2];
  const float* Woff  = (const float*)d_in[3];
  const float* boff  = (const float*)d_in[4];
  const float* Wattn = (const float*)d_in[5];
  const float* battn = (const float*)d_in[6];
  float* out = (float*)d_out;

  char* ws = (char*)d_ws;
  _Float16* vh = (_Float16*)ws;                    // 22,282,240 B
  _Float16* lh = (_Float16*)(ws + 22282240);       // 25,165,824 B

  fused_kernel<<<GEMM_BLOCKS + CONV_BLOCKS, 256, 0, stream>>>(
      query, Woff, Wattn, boff, battn, value, lh, vh);
  sample_kernel<<<16384, 256, 0, stream>>>(vh, refp, lh, out);
}

// Round 9
// 218.760 us; speedup vs baseline: 1.0998x; 1.0998x over previous
//
#include <hip/hip_runtime.h>
#include <hip/hip_bf16.h>

// HorizonTemporalSelfAttention: multi-scale deformable attention
// bs=2, nq=16384, E=256, NH=8, NL=4, NP=4, d=32, total tokens=21760
//
// R7:  logits stored as per-(b,h,q) 48-half records [32 off | 16 attn].
// R8:  XCD-aware sampler swizzle (FETCH 126->43 MB; taps L2-resident).
// R9 (REVERTED): 1-thread-per-query broke intra-line coalescing. Lesson:
//      keep 4 lanes x 16B = one 64B segment per tap in ONE instruction.
// R12/R13: reg-pipeline attempts: allocator sank the loads (VGPR stuck 52).
// R14: level-split (thread = q,l,c4). Occupancy 38->64 -- latency hidden,
//      but 16x-duplicated softmax ate the win.
// R15: softmax in GEMM epilogue: fused_kernel exposed at 85 us, occupancy
//      21% -- the 45KB __shared__ is allocated by ALL 11648 blocks incl.
//      10880 conv blocks (3 blocks/CU cap on a streaming workload).
// R16: SPLIT kernels: gemm (768 blk, plain R13 epilogue) + conv (grid-
//      stride, no LDS, full occupancy) + sampler with 1-chain preamble
//      softmax (16 q x 16 slots = 256 thr, shfl_xor in 16-lane groups,
//      weights shared via 512B LDS table).

typedef __attribute__((ext_vector_type(4))) float    float4v;
typedef __attribute__((ext_vector_type(8))) _Float16 half8;
typedef __attribute__((ext_vector_type(4))) _Float16 half4;
typedef __attribute__((ext_vector_type(2))) _Float16 half2v;

#define NQ    16384
#define NTOK  21760
#define LREC  48          // halves per (b,h,q) record: 32 off | 16 logits

#define GEMM_BLOCKS 768   // 256 M-tiles x 3 N-tiles
#define CONV_GRID   2048  // grid-stride over 2,785,280 float4
#define CONV_N4     2785280

union H8 { half8 v; half2v p[4]; };

// ---------------- K-G: logit GEMM ----------------
#define LDSTR 88
__global__ __launch_bounds__(256) void gemm_kernel(
    const float* __restrict__ qf,
    const float* __restrict__ Woff, const float* __restrict__ Wattn,
    const float* __restrict__ boff, const float* __restrict__ battn,
    _Float16* __restrict__ lh) {
  const int tid = threadIdx.x;

  __shared__ _Float16 As[128 * LDSTR];
  __shared__ _Float16 Bs[128 * LDSTR];

  const int lane = tid & 63;
  const int wv   = tid >> 6;
  const int wm   = wv >> 1, wn = wv & 1;
  const int quad = lane >> 4;
  const int r    = lane & 15;
  const int blockM = (blockIdx.x & 255) * 128;
  const int n0     = (blockIdx.x >> 8) * 128;

  float4v acc[4][4];
#pragma unroll
  for (int i = 0; i < 4; ++i)
#pragma unroll
    for (int j = 0; j < 4; ++j) acc[i][j] = (float4v){0.f, 0.f, 0.f, 0.f};

  for (int kc = 0; kc < 4; ++kc) {
    const int k0 = kc * 64;
    if (kc) __syncthreads();
    // A: 128 rows x 16 float4 k-cols, f32 -> f16
#pragma unroll
    for (int it = 0; it < 8; ++it) {
      int idx = it * 256 + tid;
      int row = idx >> 4, k4 = idx & 15;
      float4v v = *(const float4v*)(qf + (size_t)(blockM + row) * 256 + k0 + k4 * 4);
      half4 o;
      o[0] = (_Float16)v[0]; o[1] = (_Float16)v[1];
      o[2] = (_Float16)v[2]; o[3] = (_Float16)v[3];
      *(half4*)&As[row * LDSTR + k4 * 4] = o;
    }
    // B: 128 rows x 16 float4 k-cols from Wcat f32 (L2-resident, 394 KB)
#pragma unroll
    for (int it = 0; it < 8; ++it) {
      int idx = it * 256 + tid;
      int row = idx >> 4, k4 = idx & 15;
      int n = n0 + row;
      const float* src = (n < 256) ? (Woff + (size_t)n * 256)
                                   : (Wattn + (size_t)(n - 256) * 256);
      float4v v = *(const float4v*)(src + k0 + k4 * 4);
      half4 o;
      o[0] = (_Float16)v[0]; o[1] = (_Float16)v[1];
      o[2] = (_Float16)v[2]; o[3] = (_Float16)v[3];
      *(half4*)&Bs[row * LDSTR + k4 * 4] = o;
    }
    __syncthreads();

#pragma unroll
    for (int kf = 0; kf < 2; ++kf) {
      const int ko = kf * 32 + quad * 8;
      half8 af[4], bf[4];
#pragma unroll
      for (int mi = 0; mi < 4; ++mi)
        af[mi] = *(const half8*)&As[(wm * 64 + mi * 16 + r) * LDSTR + ko];
#pragma unroll
      for (int ni = 0; ni < 4; ++ni)
        bf[ni] = *(const half8*)&Bs[(wn * 64 + ni * 16 + r) * LDSTR + ko];
#pragma unroll
      for (int mi = 0; mi < 4; ++mi)
#pragma unroll
        for (int ni = 0; ni < 4; ++ni)
          acc[mi][ni] = __builtin_amdgcn_mfma_f32_16x16x32_f16(af[mi], bf[ni], acc[mi][ni], 0, 0, 0);
    }
  }

  // epilogue (R13 form): raw logits + bias, f16, per-record slots
  // n -> (head, slot): n<256: h=n>>5, slot=n&31 (offsets)
  //                    n>=256: h=(n-256)>>4, slot=32+((n-256)&15)
#pragma unroll
  for (int mi = 0; mi < 4; ++mi) {
    const int mb = blockM + wm * 64 + mi * 16 + quad * 4;
#pragma unroll
    for (int ni = 0; ni < 4; ++ni) {
      const int n = n0 + wn * 64 + ni * 16 + r;
      const float bias = (n < 256) ? boff[n] : battn[n - 256];
      const int h    = (n < 256) ? (n >> 5) : ((n - 256) >> 4);
      const int slot = (n < 256) ? (n & 31) : (32 + ((n - 256) & 15));
#pragma unroll
      for (int reg = 0; reg < 4; ++reg) {
        const int bq = mb + reg;
        const int b = bq >> 14, q = bq & 16383;
        lh[((size_t)(b * 8 + h) * NQ + q) * LREC + slot] =
            (_Float16)(acc[mi][ni][reg] + bias);
      }
    }
  }
}

// ---------------- K-C: value convert f32 -> f16 (no LDS, full occupancy) ----
__global__ __launch_bounds__(256) void conv_kernel(
    const float* __restrict__ val, _Float16* __restrict__ vh) {
  for (int i = blockIdx.x * 256 + threadIdx.x; i < CONV_N4;
       i += CONV_GRID * 256) {
    float4v v = ((const float4v*)val)[i];
    half4 o;
    o[0] = (_Float16)v[0]; o[1] = (_Float16)v[1];
    o[2] = (_Float16)v[2]; o[3] = (_Float16)v[3];
    ((half4*)vh)[i] = o;
  }
}

// ---------------- K-S: sampling (level-split + preamble softmax) ----------------
// grid 16384 flat; xcd = bid&7, local = bid>>3 (0..2047),
// hb = xcd*2 + (local>>10), qt = local&1023 -> 16 queries per block.
// Preamble: thread = (q16 = tid>>4, slot = tid&15); 16-lane group holds one
// record's 16 logits -> shfl_xor softmax, weights to 512B LDS table.
// Main: thread = (c4 = tid&3, l = (tid>>2)&3, qi = tid>>4); quad of each
// (q,l) issues 4x16B adjacent per tap -> one 64B segment per instruction.
__global__ __launch_bounds__(256) void sample_kernel(
    const _Float16* __restrict__ vh, const float* __restrict__ refp,
    const _Float16* __restrict__ lh, float* __restrict__ out) {
  const int bid   = blockIdx.x;
  const int xcd   = bid & 7;
  const int local = bid >> 3;
  const int hb    = xcd * 2 + (local >> 10);  // 0..15, == b*8+h
  const int qt    = local & 1023;
  const int h     = hb & 7;
  const int b     = hb >> 3;
  const int tid = threadIdx.x;

  // ---- preamble: softmax once per query, shared via LDS ----
  __shared__ _Float16 wsm[16][16];
  {
    const int q16  = tid >> 4;
    const int slot = tid & 15;
    const float lg = (float)lh[((size_t)hb * NQ + qt * 16 + q16) * LREC + 32 + slot];
    float m = lg;
    m = fmaxf(m, __shfl_xor(m, 1));
    m = fmaxf(m, __shfl_xor(m, 2));
    m = fmaxf(m, __shfl_xor(m, 4));
    m = fmaxf(m, __shfl_xor(m, 8));
    const float e = __expf(lg - m);
    float s = e;
    s += __shfl_xor(s, 1);
    s += __shfl_xor(s, 2);
    s += __shfl_xor(s, 4);
    s += __shfl_xor(s, 8);
    wsm[q16][slot] = (_Float16)(e * (1.0f / s));
  }
  __syncthreads();

  const int c4 = tid & 3;
  const int l  = (tid >> 2) & 3;
  const int qi = tid >> 4;                    // 0..15
  const int q  = qt * 16 + qi;
  const size_t bq = (size_t)b * NQ + q;
  const _Float16* rec = lh + ((size_t)hb * NQ + q) * LREC;

  // own level's 8 offsets (layout within record: l*8 + p*2 + xy)
  const half8 oh = *(const half8*)(rec + l * 8);
  // own level's 4 normalized weights from the LDS table
  const half4 ownw = *(const half4*)&wsm[qi][l * 4];

  float4v rp0 = *(const float4v*)(refp + bq * 8);
  float4v rp1 = *(const float4v*)(refp + bq * 8 + 4);
  const float rpx[4] = {rp0[0], rp0[2], rp1[0], rp1[2]};
  const float rpy[4] = {rp0[1], rp0[3], rp1[1], rp1[3]};

  // level geometry (uniform per thread; scalar, no runtime-indexed arrays)
  const int   W    = 128 >> l;
  const float fW   = (float)W;
  const int   base = (l == 0) ? 0 : (l == 1) ? 16384 : (l == 2) ? 20480 : 21504;
  const _Float16* vlev = vh + (size_t)b * NTOK * 256 + h * 32 + c4 * 8
                            + (size_t)base * 256;

  half2v accl0 = (half2v){(_Float16)0, (_Float16)0};
  half2v accl1 = (half2v){(_Float16)0, (_Float16)0};
  half2v accl2 = (half2v){(_Float16)0, (_Float16)0};
  half2v accl3 = (half2v){(_Float16)0, (_Float16)0};

#pragma unroll
  for (int p = 0; p < 4; ++p) {
    const float a  = (float)ownw[p];          // precomputed softmax weight
    const float ox = (float)oh[p * 2];
    const float oy = (float)oh[p * 2 + 1];
    // (ref + off/shape)*2-1 through grid_sample == ref*W + off - 0.5
    const float x = rpx[p] * fW + ox - 0.5f;
    const float y = rpy[p] * fW + oy - 0.5f;
    const float xf = floorf(x), yf = floorf(y);
    const float fx = x - xf, fy = y - yf;
    const int ix = (int)xf, iy = (int)yf;
    const int ix0 = min(max(ix, 0), W - 1);
    const int ix1 = min(max(ix + 1, 0), W - 1);
    const int iy0 = min(max(iy, 0), W - 1);
    const int iy1 = min(max(iy + 1, 0), W - 1);
    const float wx0 = ((unsigned)ix       < (unsigned)W) ? 1.f - fx : 0.f;
    const float wx1 = ((unsigned)(ix + 1) < (unsigned)W) ? fx       : 0.f;
    const float wy0 = ((unsigned)iy       < (unsigned)W) ? 1.f - fy : 0.f;
    const float wy1 = ((unsigned)(iy + 1) < (unsigned)W) ? fy       : 0.f;
    const _Float16 w00 = (_Float16)(a * wx0 * wy0);
    const _Float16 w01 = (_Float16)(a * wx1 * wy0);
    const _Float16 w10 = (_Float16)(a * wx0 * wy1);
    const _Float16 w11 = (_Float16)(a * wx1 * wy1);
    const half2v h00 = (half2v){w00, w00};
    const half2v h01 = (half2v){w01, w01};
    const half2v h10 = (half2v){w10, w10};
    const half2v h11 = (half2v){w11, w11};
    const _Float16* r0 = vlev + (size_t)(iy0 * W) * 256;
    const _Float16* r1 = vlev + (size_t)(iy1 * W) * 256;
    H8 t00, t01, t10, t11;
    t00.v = *(const half8*)(r0 + ix0 * 256);
    t01.v = *(const half8*)(r0 + ix1 * 256);
    t10.v = *(const half8*)(r1 + ix0 * 256);
    t11.v = *(const half8*)(r1 + ix1 * 256);
    accl0 += h00 * t00.p[0] + h01 * t01.p[0] + h10 * t10.p[0] + h11 * t11.p[0];
    accl1 += h00 * t00.p[1] + h01 * t01.p[1] + h10 * t10.p[1] + h11 * t11.p[1];
    accl2 += h00 * t00.p[2] + h01 * t01.p[2] + h10 * t10.p[2] + h11 * t11.p[2];
    accl3 += h00 * t00.p[3] + h01 * t01.p[3] + h10 * t10.p[3] + h11 * t11.p[3];
  }

  // flush level accumulator to f32 (channels c4*8 .. c4*8+7)
  float acc0[4], acc1[4];
  acc0[0] = (float)accl0[0]; acc0[1] = (float)accl0[1];
  acc0[2] = (float)accl1[0]; acc0[3] = (float)accl1[1];
  acc1[0] = (float)accl2[0]; acc1[1] = (float)accl2[1];
  acc1[2] = (float)accl3[0]; acc1[3] = (float)accl3[1];

  // LDS cross-level reduce + transposed coalesced store.
  __shared__ float sm[4][16][33];
#pragma unroll
  for (int j = 0; j < 4; ++j) {
    sm[l][qi][c4 * 8 + j]     = acc0[j];
    sm[l][qi][c4 * 8 + 4 + j] = acc1[j];
  }
  __syncthreads();
  // 512 outputs (32c x 16q), 2 per thread; sum levels IN ORDER.
  const size_t obase = ((size_t)b * 256 + h * 32) * NQ + qt * 16;
#pragma unroll
  for (int i = 0; i < 2; ++i) {
    const int idx = i * 256 + tid;
    const int c  = idx >> 4;
    const int ql = idx & 15;
    const float v = ((sm[0][ql][c] + sm[1][ql][c]) + sm[2][ql][c]) + sm[3][ql][c];
    out[obase + (size_t)c * NQ + ql] = v;
  }
}

extern "C" void kernel_launch(void* const* d_in, const int* in_sizes, int n_in,
                              void* d_out, int out_size, void* d_ws, size_t ws_size,
                              hipStream_t stream) {
  const float* query = (const float*)d_in[0];
  const float* value = (const float*)d_in[1];
  const float* refp  = (const float*)d_in[2];
  const float* Woff  = (const float*)d_in[3];
  const float* boff  = (const float*)d_in[4];
  const float* Wattn = (const float*)d_in[5];
  const float* battn = (const float*)d_in[6];
  float* out = (float*)d_out;

  char* ws = (char*)d_ws;
  _Float16* vh = (_Float16*)ws;                    // 22,282,240 B
  _Float16* lh = (_Float16*)(ws + 22282240);       // 25,165,824 B

  gemm_kernel<<<GEMM_BLOCKS, 256, 0, stream>>>(
      query, Woff, Wattn, boff, battn, lh);
  conv_kernel<<<CONV_GRID, 256, 0, stream>>>(value, vh);
  sample_kernel<<<16384, 256, 0, stream>>>(vh, refp, lh, out);
}

// Round 10
// 203.012 us; speedup vs baseline: 1.1851x; 1.0776x over previous
//
#include <hip/hip_runtime.h>
#include <hip/hip_bf16.h>

// HorizonTemporalSelfAttention: multi-scale deformable attention
// bs=2, nq=16384, E=256, NH=8, NL=4, NP=4, d=32, total tokens=21760
//
// R8:  XCD-aware sampler swizzle (taps L2-resident).
// R9 (REVERTED): broke intra-line coalescing -> 4x transactions, 3x time.
// R12/R13: reg pipelines; allocator defeated them (~4% each).
// R14/R16: level-split + split kernels + preamble softmax. Occupancy 73%,
//      VALU/latency no longer binding. KEY FINDING: sampler stuck 73-81 us
//      across 5 schedule variants -> bound by tap TRANSACTION throughput
//      (16.8M random 64B quad-segments, ~13.5 TB/s effective).
// R17: head-major value layout vh[b*8+h][tok][32ch]. Bilinear x-pair
//      (ix,ix+1) becomes adjacent 64B blocks -> same 128B line 50% of the
//      time => expected tap line-fills per point 4 -> 3. Conv rewritten to
//      emit the layout (XCD-swizzled so slices are born in the right L2).
//      Sampler blend math bit-identical.

typedef __attribute__((ext_vector_type(4))) float    float4v;
typedef __attribute__((ext_vector_type(8))) _Float16 half8;
typedef __attribute__((ext_vector_type(4))) _Float16 half4;
typedef __attribute__((ext_vector_type(2))) _Float16 half2v;

#define NQ    16384
#define NTOK  21760
#define LREC  48          // halves per (b,h,q) record: 32 off | 16 logits

#define GEMM_BLOCKS 768   // 256 M-tiles x 3 N-tiles
#define CONV_BLOCKS 5440  // 16 hb-slices x 340 token-tiles of 64

union H8 { half8 v; half2v p[4]; };

// ---------------- K-G: logit GEMM ----------------
#define LDSTR 88
__global__ __launch_bounds__(256) void gemm_kernel(
    const float* __restrict__ qf,
    const float* __restrict__ Woff, const float* __restrict__ Wattn,
    const float* __restrict__ boff, const float* __restrict__ battn,
    _Float16* __restrict__ lh) {
  const int tid = threadIdx.x;

  __shared__ _Float16 As[128 * LDSTR];
  __shared__ _Float16 Bs[128 * LDSTR];

  const int lane = tid & 63;
  const int wv   = tid >> 6;
  const int wm   = wv >> 1, wn = wv & 1;
  const int quad = lane >> 4;
  const int r    = lane & 15;
  const int blockM = (blockIdx.x & 255) * 128;
  const int n0     = (blockIdx.x >> 8) * 128;

  float4v acc[4][4];
#pragma unroll
  for (int i = 0; i < 4; ++i)
#pragma unroll
    for (int j = 0; j < 4; ++j) acc[i][j] = (float4v){0.f, 0.f, 0.f, 0.f};

  for (int kc = 0; kc < 4; ++kc) {
    const int k0 = kc * 64;
    if (kc) __syncthreads();
    // A: 128 rows x 16 float4 k-cols, f32 -> f16
#pragma unroll
    for (int it = 0; it < 8; ++it) {
      int idx = it * 256 + tid;
      int row = idx >> 4, k4 = idx & 15;
      float4v v = *(const float4v*)(qf + (size_t)(blockM + row) * 256 + k0 + k4 * 4);
      half4 o;
      o[0] = (_Float16)v[0]; o[1] = (_Float16)v[1];
      o[2] = (_Float16)v[2]; o[3] = (_Float16)v[3];
      *(half4*)&As[row * LDSTR + k4 * 4] = o;
    }
    // B: 128 rows x 16 float4 k-cols from Wcat f32 (L2-resident, 394 KB)
#pragma unroll
    for (int it = 0; it < 8; ++it) {
      int idx = it * 256 + tid;
      int row = idx >> 4, k4 = idx & 15;
      int n = n0 + row;
      const float* src = (n < 256) ? (Woff + (size_t)n * 256)
                                   : (Wattn + (size_t)(n - 256) * 256);
      float4v v = *(const float4v*)(src + k0 + k4 * 4);
      half4 o;
      o[0] = (_Float16)v[0]; o[1] = (_Float16)v[1];
      o[2] = (_Float16)v[2]; o[3] = (_Float16)v[3];
      *(half4*)&Bs[row * LDSTR + k4 * 4] = o;
    }
    __syncthreads();

#pragma unroll
    for (int kf = 0; kf < 2; ++kf) {
      const int ko = kf * 32 + quad * 8;
      half8 af[4], bf[4];
#pragma unroll
      for (int mi = 0; mi < 4; ++mi)
        af[mi] = *(const half8*)&As[(wm * 64 + mi * 16 + r) * LDSTR + ko];
#pragma unroll
      for (int ni = 0; ni < 4; ++ni)
        bf[ni] = *(const half8*)&Bs[(wn * 64 + ni * 16 + r) * LDSTR + ko];
#pragma unroll
      for (int mi = 0; mi < 4; ++mi)
#pragma unroll
        for (int ni = 0; ni < 4; ++ni)
          acc[mi][ni] = __builtin_amdgcn_mfma_f32_16x16x32_f16(af[mi], bf[ni], acc[mi][ni], 0, 0, 0);
    }
  }

  // epilogue: raw logits + bias, f16, per-record slots
  // n -> (head, slot): n<256: h=n>>5, slot=n&31 (offsets)
  //                    n>=256: h=(n-256)>>4, slot=32+((n-256)&15)
#pragma unroll
  for (int mi = 0; mi < 4; ++mi) {
    const int mb = blockM + wm * 64 + mi * 16 + quad * 4;
#pragma unroll
    for (int ni = 0; ni < 4; ++ni) {
      const int n = n0 + wn * 64 + ni * 16 + r;
      const float bias = (n < 256) ? boff[n] : battn[n - 256];
      const int h    = (n < 256) ? (n >> 5) : ((n - 256) >> 4);
      const int slot = (n < 256) ? (n & 31) : (32 + ((n - 256) & 15));
#pragma unroll
      for (int reg = 0; reg < 4; ++reg) {
        const int bq = mb + reg;
        const int b = bq >> 14, q = bq & 16383;
        lh[((size_t)(b * 8 + h) * NQ + q) * LREC + slot] =
            (_Float16)(acc[mi][ni][reg] + bias);
      }
    }
  }
}

// ---------------- K-C: value convert + head-major transpose ----------------
// vh layout: [(b*8+h)][tok][32ch] f16 (slice = 1.36 MB contiguous).
// grid 5440 = 8 xcd x (2 slices x 340 token-tiles); block 256 = 64 tok x 4 c8.
// Writes: wave = 16 tok x 4 c8 x 16B = 1KB contiguous. XCD swizzle puts each
// slice's written lines in its pinned XCD's L2 before the sampler runs.
__global__ __launch_bounds__(256) void conv_kernel(
    const float* __restrict__ val, _Float16* __restrict__ vh) {
  const int bid   = blockIdx.x;
  const int xcd   = bid & 7;
  const int local = bid >> 3;                 // 0..679
  const int sl    = (local >= 340) ? 1 : 0;
  const int hb    = xcd * 2 + sl;             // 0..15 == b*8+h
  const int tokT  = local - sl * 340;
  const int tid   = threadIdx.x;
  const int c8    = tid & 3;
  const int tok   = tokT * 64 + (tid >> 2);
  const int b     = hb >> 3, h = hb & 7;

  const float* src = val + ((size_t)b * NTOK + tok) * 256 + h * 32 + c8 * 8;
  float4v v0 = *(const float4v*)src;
  float4v v1 = *(const float4v*)(src + 4);
  half8 o;
  o[0] = (_Float16)v0[0]; o[1] = (_Float16)v0[1];
  o[2] = (_Float16)v0[2]; o[3] = (_Float16)v0[3];
  o[4] = (_Float16)v1[0]; o[5] = (_Float16)v1[1];
  o[6] = (_Float16)v1[2]; o[7] = (_Float16)v1[3];
  *(half8*)(vh + ((size_t)hb * NTOK + tok) * 32 + c8 * 8) = o;
}

// ---------------- K-S: sampling (level-split + preamble softmax) ----------------
// grid 16384 flat; xcd = bid&7, local = bid>>3 (0..2047),
// hb = xcd*2 + (local>>10), qt = local&1023 -> 16 queries per block.
// Preamble: 16-lane group softmax -> 512B LDS weight table.
// Main: thread = (c4, l, qi); quad of each (q,l) issues 4x16B adjacent per
// tap -> one 64B segment; x-pair taps are adjacent 64B blocks (R17 layout).
__global__ __launch_bounds__(256) void sample_kernel(
    const _Float16* __restrict__ vh, const float* __restrict__ refp,
    const _Float16* __restrict__ lh, float* __restrict__ out) {
  const int bid   = blockIdx.x;
  const int xcd   = bid & 7;
  const int local = bid >> 3;
  const int hb    = xcd * 2 + (local >> 10);  // 0..15, == b*8+h
  const int qt    = local & 1023;
  const int h     = hb & 7;
  const int b     = hb >> 3;
  const int tid = threadIdx.x;

  // ---- preamble: softmax once per query, shared via LDS ----
  __shared__ _Float16 wsm[16][16];
  {
    const int q16  = tid >> 4;
    const int slot = tid & 15;
    const float lg = (float)lh[((size_t)hb * NQ + qt * 16 + q16) * LREC + 32 + slot];
    float m = lg;
    m = fmaxf(m, __shfl_xor(m, 1));
    m = fmaxf(m, __shfl_xor(m, 2));
    m = fmaxf(m, __shfl_xor(m, 4));
    m = fmaxf(m, __shfl_xor(m, 8));
    const float e = __expf(lg - m);
    float s = e;
    s += __shfl_xor(s, 1);
    s += __shfl_xor(s, 2);
    s += __shfl_xor(s, 4);
    s += __shfl_xor(s, 8);
    wsm[q16][slot] = (_Float16)(e * (1.0f / s));
  }
  __syncthreads();

  const int c4 = tid & 3;
  const int l  = (tid >> 2) & 3;
  const int qi = tid >> 4;                    // 0..15
  const int q  = qt * 16 + qi;
  const size_t bq = (size_t)b * NQ + q;
  const _Float16* rec = lh + ((size_t)hb * NQ + q) * LREC;

  // own level's 8 offsets (layout within record: l*8 + p*2 + xy)
  const half8 oh = *(const half8*)(rec + l * 8);
  // own level's 4 normalized weights from the LDS table
  const half4 ownw = *(const half4*)&wsm[qi][l * 4];

  float4v rp0 = *(const float4v*)(refp + bq * 8);
  float4v rp1 = *(const float4v*)(refp + bq * 8 + 4);
  const float rpx[4] = {rp0[0], rp0[2], rp1[0], rp1[2]};
  const float rpy[4] = {rp0[1], rp0[3], rp1[1], rp1[3]};

  // level geometry (uniform per thread; scalar, no runtime-indexed arrays)
  const int   W    = 128 >> l;
  const float fW   = (float)W;
  const int   base = (l == 0) ? 0 : (l == 1) ? 16384 : (l == 2) ? 20480 : 21504;
  // head-major layout: slice hb, token stride 32 halves (64B)
  const _Float16* vlev = vh + ((size_t)hb * NTOK + base) * 32 + c4 * 8;

  half2v accl0 = (half2v){(_Float16)0, (_Float16)0};
  half2v accl1 = (half2v){(_Float16)0, (_Float16)0};
  half2v accl2 = (half2v){(_Float16)0, (_Float16)0};
  half2v accl3 = (half2v){(_Float16)0, (_Float16)0};

#pragma unroll
  for (int p = 0; p < 4; ++p) {
    const float a  = (float)ownw[p];          // precomputed softmax weight
    const float ox = (float)oh[p * 2];
    const float oy = (float)oh[p * 2 + 1];
    // (ref + off/shape)*2-1 through grid_sample == ref*W + off - 0.5
    const float x = rpx[p] * fW + ox - 0.5f;
    const float y = rpy[p] * fW + oy - 0.5f;
    const float xf = floorf(x), yf = floorf(y);
    const float fx = x - xf, fy = y - yf;
    const int ix = (int)xf, iy = (int)yf;
    const int ix0 = min(max(ix, 0), W - 1);
    const int ix1 = min(max(ix + 1, 0), W - 1);
    const int iy0 = min(max(iy, 0), W - 1);
    const int iy1 = min(max(iy + 1, 0), W - 1);
    const float wx0 = ((unsigned)ix       < (unsigned)W) ? 1.f - fx : 0.f;
    const float wx1 = ((unsigned)(ix + 1) < (unsigned)W) ? fx       : 0.f;
    const float wy0 = ((unsigned)iy       < (unsigned)W) ? 1.f - fy : 0.f;
    const float wy1 = ((unsigned)(iy + 1) < (unsigned)W) ? fy       : 0.f;
    const _Float16 w00 = (_Float16)(a * wx0 * wy0);
    const _Float16 w01 = (_Float16)(a * wx1 * wy0);
    const _Float16 w10 = (_Float16)(a * wx0 * wy1);
    const _Float16 w11 = (_Float16)(a * wx1 * wy1);
    const half2v h00 = (half2v){w00, w00};
    const half2v h01 = (half2v){w01, w01};
    const half2v h10 = (half2v){w10, w10};
    const half2v h11 = (half2v){w11, w11};
    // taps: token = y*W + x, 64B per token; x-pair = adjacent 64B blocks
    const _Float16* r0 = vlev + (size_t)(iy0 * W) * 32;
    const _Float16* r1 = vlev + (size_t)(iy1 * W) * 32;
    H8 t00, t01, t10, t11;
    t00.v = *(const half8*)(r0 + ix0 * 32);
    t01.v = *(const half8*)(r0 + ix1 * 32);
    t10.v = *(const half8*)(r1 + ix0 * 32);
    t11.v = *(const half8*)(r1 + ix1 * 32);
    accl0 += h00 * t00.p[0] + h01 * t01.p[0] + h10 * t10.p[0] + h11 * t11.p[0];
    accl1 += h00 * t00.p[1] + h01 * t01.p[1] + h10 * t10.p[1] + h11 * t11.p[1];
    accl2 += h00 * t00.p[2] + h01 * t01.p[2] + h10 * t10.p[2] + h11 * t11.p[2];
    accl3 += h00 * t00.p[3] + h01 * t01.p[3] + h10 * t10.p[3] + h11 * t11.p[3];
  }

  // flush level accumulator to f32 (channels c4*8 .. c4*8+7)
  float acc0[4], acc1[4];
  acc0[0] = (float)accl0[0]; acc0[1] = (float)accl0[1];
  acc0[2] = (float)accl1[0]; acc0[3] = (float)accl1[1];
  acc1[0] = (float)accl2[0]; acc1[1] = (float)accl2[1];
  acc1[2] = (float)accl3[0]; acc1[3] = (float)accl3[1];

  // LDS cross-level reduce + transposed coalesced store.
  __shared__ float sm[4][16][33];
#pragma unroll
  for (int j = 0; j < 4; ++j) {
    sm[l][qi][c4 * 8 + j]     = acc0[j];
    sm[l][qi][c4 * 8 + 4 + j] = acc1[j];
  }
  __syncthreads();
  // 512 outputs (32c x 16q), 2 per thread; sum levels IN ORDER.
  const size_t obase = ((size_t)b * 256 + h * 32) * NQ + qt * 16;
#pragma unroll
  for (int i = 0; i < 2; ++i) {
    const int idx = i * 256 + tid;
    const int c  = idx >> 4;
    const int ql = idx & 15;
    const float v = ((sm[0][ql][c] + sm[1][ql][c]) + sm[2][ql][c]) + sm[3][ql][c];
    out[obase + (size_t)c * NQ + ql] = v;
  }
}

extern "C" void kernel_launch(void* const* d_in, const int* in_sizes, int n_in,
                              void* d_out, int out_size, void* d_ws, size_t ws_size,
                              hipStream_t stream) {
  const float* query = (const float*)d_in[0];
  const float* value = (const float*)d_in[1];
  const float* refp  = (const float*)d_in[2];
  const float* Woff  = (const float*)d_in[3];
  const float* boff  = (const float*)d_in[4];
  const float* Wattn = (const float*)d_in[5];
  const float* battn = (const float*)d_in[6];
  float* out = (float*)d_out;

  char* ws = (char*)d_ws;
  _Float16* vh = (_Float16*)ws;                    // 22,282,240 B (head-major)
  _Float16* lh = (_Float16*)(ws + 22282240);       // 25,165,824 B

  gemm_kernel<<<GEMM_BLOCKS, 256, 0, stream>>>(
      query, Woff, Wattn, boff, battn, lh);
  conv_kernel<<<CONV_BLOCKS, 256, 0, stream>>>(value, vh);
  sample_kernel<<<16384, 256, 0, stream>>>(vh, refp, lh, out);
}

// Round 11
// 202.778 us; speedup vs baseline: 1.1864x; 1.0012x over previous
//
#include <hip/hip_runtime.h>
#include <hip/hip_bf16.h>

// HorizonTemporalSelfAttention: multi-scale deformable attention
// bs=2, nq=16384, E=256, NH=8, NL=4, NP=4, d=32, total tokens=21760
//
// R8:  XCD-aware sampler swizzle (taps L2-resident).
// R9 (REVERTED): broke intra-line coalescing -> 4x transactions, 3x time.
// R14/R16: level-split + split kernels + preamble softmax.
// R17: head-major vh[b*8+h][tok][32ch]: x-pair same 128B line when ix even
//      -> lines/point 4->3, sampler 79.5->62.3 us. CONFIRMED MODEL: sampler
//      time = line-fill throughput; ~44 us VALU hidden underneath.
// R18: paired-token layout: 128B entry e = [token e | token e+1] (2x mem).
//      Any x-pair = ONE aligned entry -> 2 line-fills/point always (-33%).
//      Anchor = unclamped ix clamped to [-1,W-1]; dense global entries make
//      edges self-correct (zero-weight taps read finite data/zeroed pads).
//      Host guards ws_size (needs 69.7MB); falls back to R17 kernels.

typedef __attribute__((ext_vector_type(4))) float    float4v;
typedef __attribute__((ext_vector_type(8))) _Float16 half8;
typedef __attribute__((ext_vector_type(4))) _Float16 half4;
typedef __attribute__((ext_vector_type(2))) _Float16 half2v;

#define NQ    16384
#define NTOK  21760
#define LREC  48          // halves per (b,h,q) record: 32 off | 16 logits

#define GEMM_BLOCKS 768   // 256 M-tiles x 3 N-tiles
#define CONV_BLOCKS 5440  // 16 hb-slices x 340 token-tiles of 64
#define SLICE_H 1392704   // halves per pair-slice: (NTOK+1)*64 (incl. front pad)

union H8 { half8 v; half2v p[4]; };

// ---------------- K-G: logit GEMM (unchanged) ----------------
#define LDSTR 88
__global__ __launch_bounds__(256) void gemm_kernel(
    const float* __restrict__ qf,
    const float* __restrict__ Woff, const float* __restrict__ Wattn,
    const float* __restrict__ boff, const float* __restrict__ battn,
    _Float16* __restrict__ lh) {
  const int tid = threadIdx.x;

  __shared__ _Float16 As[128 * LDSTR];
  __shared__ _Float16 Bs[128 * LDSTR];

  const int lane = tid & 63;
  const int wv   = tid >> 6;
  const int wm   = wv >> 1, wn = wv & 1;
  const int quad = lane >> 4;
  const int r    = lane & 15;
  const int blockM = (blockIdx.x & 255) * 128;
  const int n0     = (blockIdx.x >> 8) * 128;

  float4v acc[4][4];
#pragma unroll
  for (int i = 0; i < 4; ++i)
#pragma unroll
    for (int j = 0; j < 4; ++j) acc[i][j] = (float4v){0.f, 0.f, 0.f, 0.f};

  for (int kc = 0; kc < 4; ++kc) {
    const int k0 = kc * 64;
    if (kc) __syncthreads();
#pragma unroll
    for (int it = 0; it < 8; ++it) {
      int idx = it * 256 + tid;
      int row = idx >> 4, k4 = idx & 15;
      float4v v = *(const float4v*)(qf + (size_t)(blockM + row) * 256 + k0 + k4 * 4);
      half4 o;
      o[0] = (_Float16)v[0]; o[1] = (_Float16)v[1];
      o[2] = (_Float16)v[2]; o[3] = (_Float16)v[3];
      *(half4*)&As[row * LDSTR + k4 * 4] = o;
    }
#pragma unroll
    for (int it = 0; it < 8; ++it) {
      int idx = it * 256 + tid;
      int row = idx >> 4, k4 = idx & 15;
      int n = n0 + row;
      const float* src = (n < 256) ? (Woff + (size_t)n * 256)
                                   : (Wattn + (size_t)(n - 256) * 256);
      float4v v = *(const float4v*)(src + k0 + k4 * 4);
      half4 o;
      o[0] = (_Float16)v[0]; o[1] = (_Float16)v[1];
      o[2] = (_Float16)v[2]; o[3] = (_Float16)v[3];
      *(half4*)&Bs[row * LDSTR + k4 * 4] = o;
    }
    __syncthreads();

#pragma unroll
    for (int kf = 0; kf < 2; ++kf) {
      const int ko = kf * 32 + quad * 8;
      half8 af[4], bf[4];
#pragma unroll
      for (int mi = 0; mi < 4; ++mi)
        af[mi] = *(const half8*)&As[(wm * 64 + mi * 16 + r) * LDSTR + ko];
#pragma unroll
      for (int ni = 0; ni < 4; ++ni)
        bf[ni] = *(const half8*)&Bs[(wn * 64 + ni * 16 + r) * LDSTR + ko];
#pragma unroll
      for (int mi = 0; mi < 4; ++mi)
#pragma unroll
        for (int ni = 0; ni < 4; ++ni)
          acc[mi][ni] = __builtin_amdgcn_mfma_f32_16x16x32_f16(af[mi], bf[ni], acc[mi][ni], 0, 0, 0);
    }
  }

#pragma unroll
  for (int mi = 0; mi < 4; ++mi) {
    const int mb = blockM + wm * 64 + mi * 16 + quad * 4;
#pragma unroll
    for (int ni = 0; ni < 4; ++ni) {
      const int n = n0 + wn * 64 + ni * 16 + r;
      const float bias = (n < 256) ? boff[n] : battn[n - 256];
      const int h    = (n < 256) ? (n >> 5) : ((n - 256) >> 4);
      const int slot = (n < 256) ? (n & 31) : (32 + ((n - 256) & 15));
#pragma unroll
      for (int reg = 0; reg < 4; ++reg) {
        const int bq = mb + reg;
        const int b = bq >> 14, q = bq & 16383;
        lh[((size_t)(b * 8 + h) * NQ + q) * LREC + slot] =
            (_Float16)(acc[mi][ni][reg] + bias);
      }
    }
  }
}

// ---------------- K-C (pair): convert + paired-token transpose ----------------
// vh pair layout per slice: [64h front pad][entry 0..21759, 64h each]
// entry e = [token e (32h) | token e+1 (32h)]. Token t written to entry t
// half0 and entry t-1 half1. Pads zeroed (front half0; entry 21759 half1).
__global__ __launch_bounds__(256) void conv_pair_kernel(
    const float* __restrict__ val, _Float16* __restrict__ vh) {
  const int bid   = blockIdx.x;
  const int xcd   = bid & 7;
  const int local = bid >> 3;                 // 0..679
  const int sl    = (local >= 340) ? 1 : 0;
  const int hb    = xcd * 2 + sl;             // 0..15 == b*8+h
  const int tokT  = local - sl * 340;
  const int tid   = threadIdx.x;
  const int c8    = tid & 3;
  const int tok   = tokT * 64 + (tid >> 2);
  const int b     = hb >> 3, h = hb & 7;

  const float* src = val + ((size_t)b * NTOK + tok) * 256 + h * 32 + c8 * 8;
  float4v v0 = *(const float4v*)src;
  float4v v1 = *(const float4v*)(src + 4);
  half8 o;
  o[0] = (_Float16)v0[0]; o[1] = (_Float16)v0[1];
  o[2] = (_Float16)v0[2]; o[3] = (_Float16)v0[3];
  o[4] = (_Float16)v1[0]; o[5] = (_Float16)v1[1];
  o[6] = (_Float16)v1[2]; o[7] = (_Float16)v1[3];

  _Float16* sd = vh + (size_t)hb * SLICE_H + 64;   // slice data (entry 0)
  *(half8*)(sd + (size_t)tok * 64 + c8 * 8)      = o;  // entry tok, half0
  *(half8*)(sd + (size_t)tok * 64 - 32 + c8 * 8) = o;  // entry tok-1, half1
  if (tok == 0) {
    half8 z;
#pragma unroll
    for (int k = 0; k < 8; ++k) z[k] = (_Float16)0;
    *(half8*)(sd - 64 + c8 * 8) = z;                   // front pad half0
  }
  if (tok == NTOK - 1) {
    half8 z;
#pragma unroll
    for (int k = 0; k < 8; ++k) z[k] = (_Float16)0;
    *(half8*)(sd + (size_t)NTOK * 64 - 32 + c8 * 8) = z; // entry 21759 half1
  }
}

// ---------------- K-S (pair): sampling on paired-token layout ----------------
__global__ __launch_bounds__(256) void sample_pair_kernel(
    const _Float16* __restrict__ vh, const float* __restrict__ refp,
    const _Float16* __restrict__ lh, float* __restrict__ out) {
  const int bid   = blockIdx.x;
  const int xcd   = bid & 7;
  const int local = bid >> 3;
  const int hb    = xcd * 2 + (local >> 10);  // 0..15, == b*8+h
  const int qt    = local & 1023;
  const int h     = hb & 7;
  const int b     = hb >> 3;
  const int tid = threadIdx.x;

  // ---- preamble: softmax once per query, shared via LDS ----
  __shared__ _Float16 wsm[16][16];
  {
    const int q16  = tid >> 4;
    const int slot = tid & 15;
    const float lg = (float)lh[((size_t)hb * NQ + qt * 16 + q16) * LREC + 32 + slot];
    float m = lg;
    m = fmaxf(m, __shfl_xor(m, 1));
    m = fmaxf(m, __shfl_xor(m, 2));
    m = fmaxf(m, __shfl_xor(m, 4));
    m = fmaxf(m, __shfl_xor(m, 8));
    const float e = __expf(lg - m);
    float s = e;
    s += __shfl_xor(s, 1);
    s += __shfl_xor(s, 2);
    s += __shfl_xor(s, 4);
    s += __shfl_xor(s, 8);
    wsm[q16][slot] = (_Float16)(e * (1.0f / s));
  }
  __syncthreads();

  const int c4 = tid & 3;
  const int l  = (tid >> 2) & 3;
  const int qi = tid >> 4;                    // 0..15
  const int q  = qt * 16 + qi;
  const size_t bq = (size_t)b * NQ + q;
  const _Float16* rec = lh + ((size_t)hb * NQ + q) * LREC;

  const half8 oh = *(const half8*)(rec + l * 8);
  const half4 ownw = *(const half4*)&wsm[qi][l * 4];

  float4v rp0 = *(const float4v*)(refp + bq * 8);
  float4v rp1 = *(const float4v*)(refp + bq * 8 + 4);
  const float rpx[4] = {rp0[0], rp0[2], rp1[0], rp1[2]};
  const float rpy[4] = {rp0[1], rp0[3], rp1[1], rp1[3]};

  const int   W    = 128 >> l;
  const float fW   = (float)W;
  const int   base = (l == 0) ? 0 : (l == 1) ? 16384 : (l == 2) ? 20480 : 21504;
  // pair layout: entry stride 64 halves; vlev points at entry(base), own slice
  const _Float16* vlev = vh + (size_t)hb * SLICE_H + 64 + (size_t)base * 64 + c4 * 8;

  half2v accl0 = (half2v){(_Float16)0, (_Float16)0};
  half2v accl1 = (half2v){(_Float16)0, (_Float16)0};
  half2v accl2 = (half2v){(_Float16)0, (_Float16)0};
  half2v accl3 = (half2v){(_Float16)0, (_Float16)0};

#pragma unroll
  for (int p = 0; p < 4; ++p) {
    const float a  = (float)ownw[p];
    const float ox = (float)oh[p * 2];
    const float oy = (float)oh[p * 2 + 1];
    const float x = rpx[p] * fW + ox - 0.5f;
    const float y = rpy[p] * fW + oy - 0.5f;
    const float xf = floorf(x), yf = floorf(y);
    const float fx = x - xf, fy = y - yf;
    const int ix = (int)xf, iy = (int)yf;
    // pair anchor: entry (iy*W + ax) holds tokens (ax, ax+1); clamp to
    // [-1, W-1] -- outside that range both wx are 0 and reads stay in-slice
    const int ax  = min(max(ix, -1), W - 1);
    const int iy0 = min(max(iy, 0), W - 1);
    const int iy1 = min(max(iy + 1, 0), W - 1);
    const float wx0 = ((unsigned)ix       < (unsigned)W) ? 1.f - fx : 0.f;
    const float wx1 = ((unsigned)(ix + 1) < (unsigned)W) ? fx       : 0.f;
    const float wy0 = ((unsigned)iy       < (unsigned)W) ? 1.f - fy : 0.f;
    const float wy1 = ((unsigned)(iy + 1) < (unsigned)W) ? fy       : 0.f;
    const _Float16 w00 = (_Float16)(a * wx0 * wy0);
    const _Float16 w01 = (_Float16)(a * wx1 * wy0);
    const _Float16 w10 = (_Float16)(a * wx0 * wy1);
    const _Float16 w11 = (_Float16)(a * wx1 * wy1);
    const half2v h00 = (half2v){w00, w00};
    const half2v h01 = (half2v){w01, w01};
    const half2v h10 = (half2v){w10, w10};
    const half2v h11 = (half2v){w11, w11};
    // one 128B entry per row: t00 = half0, t01 = half1 (+32h imm offset)
    const _Float16* e0 = vlev + (iy0 * W + ax) * 64;
    const _Float16* e1 = vlev + (iy1 * W + ax) * 64;
    H8 t00, t01, t10, t11;
    t00.v = *(const half8*)(e0);
    t01.v = *(const half8*)(e0 + 32);
    t10.v = *(const half8*)(e1);
    t11.v = *(const half8*)(e1 + 32);
    accl0 += h00 * t00.p[0] + h01 * t01.p[0] + h10 * t10.p[0] + h11 * t11.p[0];
    accl1 += h00 * t00.p[1] + h01 * t01.p[1] + h10 * t10.p[1] + h11 * t11.p[1];
    accl2 += h00 * t00.p[2] + h01 * t01.p[2] + h10 * t10.p[2] + h11 * t11.p[2];
    accl3 += h00 * t00.p[3] + h01 * t01.p[3] + h10 * t10.p[3] + h11 * t11.p[3];
  }

  float acc0[4], acc1[4];
  acc0[0] = (float)accl0[0]; acc0[1] = (float)accl0[1];
  acc0[2] = (float)accl1[0]; acc0[3] = (float)accl1[1];
  acc1[0] = (float)accl2[0]; acc1[1] = (float)accl2[1];
  acc1[2] = (float)accl3[0]; acc1[3] = (float)accl3[1];

  __shared__ float sm[4][16][33];
#pragma unroll
  for (int j = 0; j < 4; ++j) {
    sm[l][qi][c4 * 8 + j]     = acc0[j];
    sm[l][qi][c4 * 8 + 4 + j] = acc1[j];
  }
  __syncthreads();
  const size_t obase = ((size_t)b * 256 + h * 32) * NQ + qt * 16;
#pragma unroll
  for (int i = 0; i < 2; ++i) {
    const int idx = i * 256 + tid;
    const int c  = idx >> 4;
    const int ql = idx & 15;
    const float v = ((sm[0][ql][c] + sm[1][ql][c]) + sm[2][ql][c]) + sm[3][ql][c];
    out[obase + (size_t)c * NQ + ql] = v;
  }
}

// ---------------- Fallback path (R17, proven): single-copy head-major ----------
__global__ __launch_bounds__(256) void conv_kernel(
    const float* __restrict__ val, _Float16* __restrict__ vh) {
  const int bid   = blockIdx.x;
  const int xcd   = bid & 7;
  const int local = bid >> 3;
  const int sl    = (local >= 340) ? 1 : 0;
  const int hb    = xcd * 2 + sl;
  const int tokT  = local - sl * 340;
  const int tid   = threadIdx.x;
  const int c8    = tid & 3;
  const int tok   = tokT * 64 + (tid >> 2);
  const int b     = hb >> 3, h = hb & 7;

  const float* src = val + ((size_t)b * NTOK + tok) * 256 + h * 32 + c8 * 8;
  float4v v0 = *(const float4v*)src;
  float4v v1 = *(const float4v*)(src + 4);
  half8 o;
  o[0] = (_Float16)v0[0]; o[1] = (_Float16)v0[1];
  o[2] = (_Float16)v0[2]; o[3] = (_Float16)v0[3];
  o[4] = (_Float16)v1[0]; o[5] = (_Float16)v1[1];
  o[6] = (_Float16)v1[2]; o[7] = (_Float16)v1[3];
  *(half8*)(vh + ((size_t)hb * NTOK + tok) * 32 + c8 * 8) = o;
}

__global__ __launch_bounds__(256) void sample_kernel(
    const _Float16* __restrict__ vh, const float* __restrict__ refp,
    const _Float16* __restrict__ lh, float* __restrict__ out) {
  const int bid   = blockIdx.x;
  const int xcd   = bid & 7;
  const int local = bid >> 3;
  const int hb    = xcd * 2 + (local >> 10);
  const int qt    = local & 1023;
  const int h     = hb & 7;
  const int b     = hb >> 3;
  const int tid = threadIdx.x;

  __shared__ _Float16 wsm[16][16];
  {
    const int q16  = tid >> 4;
    const int slot = tid & 15;
    const float lg = (float)lh[((size_t)hb * NQ + qt * 16 + q16) * LREC + 32 + slot];
    float m = lg;
    m = fmaxf(m, __shfl_xor(m, 1));
    m = fmaxf(m, __shfl_xor(m, 2));
    m = fmaxf(m, __shfl_xor(m, 4));
    m = fmaxf(m, __shfl_xor(m, 8));
    const float e = __expf(lg - m);
    float s = e;
    s += __shfl_xor(s, 1);
    s += __shfl_xor(s, 2);
    s += __shfl_xor(s, 4);
    s += __shfl_xor(s, 8);
    wsm[q16][slot] = (_Float16)(e * (1.0f / s));
  }
  __syncthreads();

  const int c4 = tid & 3;
  const int l  = (tid >> 2) & 3;
  const int qi = tid >> 4;
  const int q  = qt * 16 + qi;
  const size_t bq = (size_t)b * NQ + q;
  const _Float16* rec = lh + ((size_t)hb * NQ + q) * LREC;

  const half8 oh = *(const half8*)(rec + l * 8);
  const half4 ownw = *(const half4*)&wsm[qi][l * 4];

  float4v rp0 = *(const float4v*)(refp + bq * 8);
  float4v rp1 = *(const float4v*)(refp + bq * 8 + 4);
  const float rpx[4] = {rp0[0], rp0[2], rp1[0], rp1[2]};
  const float rpy[4] = {rp0[1], rp0[3], rp1[1], rp1[3]};

  const int   W    = 128 >> l;
  const float fW   = (float)W;
  const int   base = (l == 0) ? 0 : (l == 1) ? 16384 : (l == 2) ? 20480 : 21504;
  const _Float16* vlev = vh + ((size_t)hb * NTOK + base) * 32 + c4 * 8;

  half2v accl0 = (half2v){(_Float16)0, (_Float16)0};
  half2v accl1 = (half2v){(_Float16)0, (_Float16)0};
  half2v accl2 = (half2v){(_Float16)0, (_Float16)0};
  half2v accl3 = (half2v){(_Float16)0, (_Float16)0};

#pragma unroll
  for (int p = 0; p < 4; ++p) {
    const float a  = (float)ownw[p];
    const float ox = (float)oh[p * 2];
    const float oy = (float)oh[p * 2 + 1];
    const float x = rpx[p] * fW + ox - 0.5f;
    const float y = rpy[p] * fW + oy - 0.5f;
    const float xf = floorf(x), yf = floorf(y);
    const float fx = x - xf, fy = y - yf;
    const int ix = (int)xf, iy = (int)yf;
    const int ix0 = min(max(ix, 0), W - 1);
    const int ix1 = min(max(ix + 1, 0), W - 1);
    const int iy0 = min(max(iy, 0), W - 1);
    const int iy1 = min(max(iy + 1, 0), W - 1);
    const float wx0 = ((unsigned)ix       < (unsigned)W) ? 1.f - fx : 0.f;
    const float wx1 = ((unsigned)(ix + 1) < (unsigned)W) ? fx       : 0.f;
    const float wy0 = ((unsigned)iy       < (unsigned)W) ? 1.f - fy : 0.f;
    const float wy1 = ((unsigned)(iy + 1) < (unsigned)W) ? fy       : 0.f;
    const _Float16 w00 = (_Float16)(a * wx0 * wy0);
    const _Float16 w01 = (_Float16)(a * wx1 * wy0);
    const _Float16 w10 = (_Float16)(a * wx0 * wy1);
    const _Float16 w11 = (_Float16)(a * wx1 * wy1);
    const half2v h00 = (half2v){w00, w00};
    const half2v h01 = (half2v){w01, w01};
    const half2v h10 = (half2v){w10, w10};
    const half2v h11 = (half2v){w11, w11};
    const _Float16* r0 = vlev + (size_t)(iy0 * W) * 32;
    const _Float16* r1 = vlev + (size_t)(iy1 * W) * 32;
    H8 t00, t01, t10, t11;
    t00.v = *(const half8*)(r0 + ix0 * 32);
    t01.v = *(const half8*)(r0 + ix1 * 32);
    t10.v = *(const half8*)(r1 + ix0 * 32);
    t11.v = *(const half8*)(r1 + ix1 * 32);
    accl0 += h00 * t00.p[0] + h01 * t01.p[0] + h10 * t10.p[0] + h11 * t11.p[0];
    accl1 += h00 * t00.p[1] + h01 * t01.p[1] + h10 * t10.p[1] + h11 * t11.p[1];
    accl2 += h00 * t00.p[2] + h01 * t01.p[2] + h10 * t10.p[2] + h11 * t11.p[2];
    accl3 += h00 * t00.p[3] + h01 * t01.p[3] + h10 * t10.p[3] + h11 * t11.p[3];
  }

  float acc0[4], acc1[4];
  acc0[0] = (float)accl0[0]; acc0[1] = (float)accl0[1];
  acc0[2] = (float)accl1[0]; acc0[3] = (float)accl1[1];
  acc1[0] = (float)accl2[0]; acc1[1] = (float)accl2[1];
  acc1[2] = (float)accl3[0]; acc1[3] = (float)accl3[1];

  __shared__ float sm[4][16][33];
#pragma unroll
  for (int j = 0; j < 4; ++j) {
    sm[l][qi][c4 * 8 + j]     = acc0[j];
    sm[l][qi][c4 * 8 + 4 + j] = acc1[j];
  }
  __syncthreads();
  const size_t obase = ((size_t)b * 256 + h * 32) * NQ + qt * 16;
#pragma unroll
  for (int i = 0; i < 2; ++i) {
    const int idx = i * 256 + tid;
    const int c  = idx >> 4;
    const int ql = idx & 15;
    const float v = ((sm[0][ql][c] + sm[1][ql][c]) + sm[2][ql][c]) + sm[3][ql][c];
    out[obase + (size_t)c * NQ + ql] = v;
  }
}

extern "C" void kernel_launch(void* const* d_in, const int* in_sizes, int n_in,
                              void* d_out, int out_size, void* d_ws, size_t ws_size,
                              hipStream_t stream) {
  const float* query = (const float*)d_in[0];
  const float* value = (const float*)d_in[1];
  const float* refp  = (const float*)d_in[2];
  const float* Woff  = (const float*)d_in[3];
  const float* boff  = (const float*)d_in[4];
  const float* Wattn = (const float*)d_in[5];
  const float* battn = (const float*)d_in[6];
  float* out = (float*)d_out;

  char* ws = (char*)d_ws;
  const size_t PAIR_VH_BYTES = (size_t)16 * SLICE_H * 2;   // 44,566,528
  const size_t LH_BYTES      = 25165824;

  if (ws_size >= PAIR_VH_BYTES + LH_BYTES) {
    _Float16* vh = (_Float16*)ws;
    _Float16* lh = (_Float16*)(ws + PAIR_VH_BYTES);
    gemm_kernel<<<GEMM_BLOCKS, 256, 0, stream>>>(
        query, Woff, Wattn, boff, battn, lh);
    conv_pair_kernel<<<CONV_BLOCKS, 256, 0, stream>>>(value, vh);
    sample_pair_kernel<<<16384, 256, 0, stream>>>(vh, refp, lh, out);
  } else {
    _Float16* vh = (_Float16*)ws;                    // 22,282,240 B
    _Float16* lh = (_Float16*)(ws + 22282240);
    gemm_kernel<<<GEMM_BLOCKS, 256, 0, stream>>>(
        query, Woff, Wattn, boff, battn, lh);
    conv_kernel<<<CONV_BLOCKS, 256, 0, stream>>>(value, vh);
    sample_kernel<<<16384, 256, 0, stream>>>(vh, refp, lh, out);
  }
}